// Round 8
// baseline (89.923 us; speedup 1.0000x reference)
//
#include <hip/hip_runtime.h>

static constexpr int T = 8192;
static constexpr int P = 64;
static constexpr int NSAMP = 8189; // T - HIST - 1
static constexpr int NBLK = 128;   // transpose blocks, 64 rows each

// ---------------- K0: transpose ts[T][64] -> tsT[64][T] + per-series minmax partials
__global__ __launch_bounds__(256) void transpose_kernel(const float* __restrict__ ts,
        float* __restrict__ tsT, float* __restrict__ pmin, float* __restrict__ pmax)
{
    __shared__ float tile[64 * 65];   // stride 65: conflict-benign
    const int tid = threadIdx.x;
    const int r0 = blockIdx.x * 64;
    const float4* ts4 = (const float4*)(ts + r0 * P);
    #pragma unroll
    for (int k = 0; k < 4; ++k) {
        int g = tid + k * 256;          // 0..1023
        int r = g >> 4, c = (g & 15) * 4;
        float4 v = ts4[g];              // coalesced
        float* dst = &tile[r * 65 + c];
        dst[0] = v.x; dst[1] = v.y; dst[2] = v.z; dst[3] = v.w;
    }
    __syncthreads();
    #pragma unroll
    for (int k = 0; k < 4; ++k) {
        int g = tid + k * 256;
        int s = g >> 4, j4 = g & 15;    // series, 4-row chunk
        float a = tile[(j4 * 4 + 0) * 65 + s];
        float b = tile[(j4 * 4 + 1) * 65 + s];
        float c = tile[(j4 * 4 + 2) * 65 + s];
        float d = tile[(j4 * 4 + 3) * 65 + s];
        float4 o; o.x = a; o.y = b; o.z = c; o.w = d;
        *(float4*)(tsT + s * T + r0 + j4 * 4) = o;   // coalesced
        float mn = fminf(fminf(a, b), fminf(c, d));
        float mx = fmaxf(fmaxf(a, b), fmaxf(c, d));
        #pragma unroll
        for (int off = 8; off > 0; off >>= 1) {      // 16 lanes share series s
            mn = fminf(mn, __shfl_down(mn, off, 16));
            mx = fmaxf(mx, __shfl_down(mx, off, 16));
        }
        if (j4 == 0) { pmin[s * NBLK + blockIdx.x] = mn; pmax[s * NBLK + blockIdx.x] = mx; }
    }
}

// ---------------- K1: prep — coalesced column read, bin in regs, emit codes + h_y ---
// Pre-scrambled codes: A[i]=((yp*320)&4095)*8+yf, X[i]=((xp*709)&4095)*8
// (320 = 64*709 mod 4096), so pair-side cell = (A+X)&0x7FFF.
__global__ __launch_bounds__(1024) void prep_kernel(const float* __restrict__ tsT,
        const float* __restrict__ pmin, const float* __restrict__ pmax,
        unsigned short* __restrict__ A, unsigned short* __restrict__ X,
        float* __restrict__ h_y)
{
    __shared__ unsigned char bins[T];   // 8 KiB
    __shared__ unsigned int cy[512];    // 2 KiB
    __shared__ float wred[4];
    const int p = blockIdx.x, tid = threadIdx.x;
    const int lane = tid & 63, wave = tid >> 6;

    if (tid < 128) {   // reduce 128 partials (waves 0,1 fully active)
        float mn = pmin[p * NBLK + tid];
        float mx = pmax[p * NBLK + tid];
        #pragma unroll
        for (int off = 32; off > 0; off >>= 1) {
            mn = fminf(mn, __shfl_down(mn, off, 64));
            mx = fmaxf(mx, __shfl_down(mx, off, 64));
        }
        if (lane == 0) { wred[wave] = mn; wred[2 + wave] = mx; }
    }
    for (int i = tid; i < 512; i += 1024) cy[i] = 0u;
    __syncthreads();
    const float xmin = fminf(wred[0], wred[1]);
    const float xmax = fmaxf(wred[2], wred[3]);
    const float rng = xmax - xmin;
    const float den = rng + 1e-8f;      // reference float32 op order
    const int flat = rng < 1e-8f;

    // bin 8 consecutive values from registers (coalesced float4 loads)
    const float4* c4p = (const float4*)(tsT + p * T);
    float4 v0 = c4p[tid * 2], v1 = c4p[tid * 2 + 1];
    float vv[8] = { v0.x, v0.y, v0.z, v0.w, v1.x, v1.y, v1.z, v1.w };
    unsigned pk0 = 0u, pk1 = 0u;
    #pragma unroll
    for (int j = 0; j < 4; ++j) {
        float n0 = (vv[j] - xmin) / den;       // IEEE div, matches reference
        float n1 = (vv[4 + j] - xmin) / den;
        int b0 = (int)(n0 * 7.0f); b0 = b0 < 0 ? 0 : (b0 > 7 ? 7 : b0);
        int b1 = (int)(n1 * 7.0f); b1 = b1 < 0 ? 0 : (b1 > 7 ? 7 : b1);
        if (flat) { b0 = 0; b1 = 0; }
        pk0 |= (unsigned)b0 << (8 * j);
        pk1 |= (unsigned)b1 << (8 * j);
    }
    *(uint2*)&bins[tid * 8] = make_uint2(pk0, pk1);
    __syncthreads();

    unsigned short* Ap = A + p * T;
    unsigned short* Xp = X + p * T;
    for (int i = tid * 4; i + 3 < NSAMP; i += 4096) {
        unsigned w0 = *(const unsigned*)&bins[i];
        unsigned w1 = *(const unsigned*)&bins[i + 4];
        unsigned long long bb = (unsigned long long)w0 | ((unsigned long long)w1 << 32);
        ushort4 av, xv;
        unsigned short* ap = (unsigned short*)&av;
        unsigned short* xp = (unsigned short*)&xv;
        #pragma unroll
        for (int j = 0; j < 4; ++j) {
            unsigned b1 = (unsigned)(bb >> (8 * (j + 1))) & 255u;
            unsigned b2 = (unsigned)(bb >> (8 * (j + 2))) & 255u;
            unsigned b3 = (unsigned)(bb >> (8 * (j + 3))) & 255u;
            unsigned yp = b2 + 8u * b1;
            ap[j] = (unsigned short)(((yp * 320u) & 4095u) * 8u + b3);
            xp[j] = (unsigned short)(((yp * 709u) & 4095u) * 8u);
            atomicAdd(&cy[yp * 8u + b3], 1u);
        }
        *(ushort4*)(Ap + i) = av;
        *(ushort4*)(Xp + i) = xv;
    }
    if (tid == 0) {  // tail: sample 8188
        unsigned b1 = bins[NSAMP], b2 = bins[NSAMP + 1], b3 = bins[NSAMP + 2];
        unsigned yp = b2 + 8u * b1;
        Ap[NSAMP - 1] = (unsigned short)(((yp * 320u) & 4095u) * 8u + b3);
        Xp[NSAMP - 1] = (unsigned short)(((yp * 709u) & 4095u) * 8u);
        atomicAdd(&cy[yp * 8u + b3], 1u);
    }
    __syncthreads();

    if (tid < 64) {
        float tot = 0.0f, sc = 0.0f;
        #pragma unroll
        for (int v = 0; v < 8; ++v) {
            unsigned c = cy[tid * 8 + v];
            if (c) { float fc = (float)c; tot += fc; sc += fc * log2f(fc); }
        }
        float acc = (tot >= 2.0f) ? (tot * log2f(tot) - sc) : 0.0f;
        #pragma unroll
        for (int off = 32; off > 0; off >>= 1) acc += __shfl_down(acc, off, 64);
        if (tid == 0) h_y[p] = acc * (1.0f / (float)NSAMP);
    }
}

// ---------------- K2: pair TE — atomic-rtn + register delta-LUT (c<8) --------------
// Joint hist 32768 u8 cells (32 KiB). sum_cells c*log2 c via telescoping:
// jacc += lut[old] per sample, lut[c]=(c+1)log2(c+1)-c*log2 c. old<8 (~97% of
// samples) resolved by a 7-cndmask register select over literal constants; only
// old>=8 touches the LDS lut (few active lanes -> near-conflict-free read).
// Tot term: slim SWAR sweep + 1 log/state. tot<2 / c<2 masks automatic.
__global__ __launch_bounds__(512, 8) void pair_kernel(const unsigned short* __restrict__ A,
        const unsigned short* __restrict__ X, const float* __restrict__ h_y,
        float* __restrict__ out)
{
    const int src = blockIdx.x >> 6, tgt = blockIdx.x & 63, tid = threadIdx.x;
    if (src == tgt) { if (tid == 0) out[blockIdx.x] = 0.0f; return; }

    __shared__ unsigned int hj[8192];   // 32768 u8 cells
    __shared__ float lut[256];          // delta LUT (used only for old>=8)
    __shared__ float red[8];

    if (tid < 256) {
        float fc = (float)tid;
        float f0 = (tid == 0) ? 0.0f : fc * log2f(fc);
        lut[tid] = (fc + 1.0f) * log2f(fc + 1.0f) - f0;
    }
    uint4* z = (uint4*)hj;
    for (int i = tid; i < 2048; i += 512) z[i] = make_uint4(0u, 0u, 0u, 0u);
    __syncthreads();

    const unsigned short* At = A + tgt * T;
    const unsigned short* Xs = X + src * T;
    float jacc = 0.0f;

    // lut[0..7] as literals: (c+1)log2(c+1) - c log2 c
    const float L0 = 0.0f,                  L1 = 2.0f;
    const float L2 = 2.7548875021634683f,   L3 = 3.2451124978365317f;
    const float L4 = 3.6096404744368117f,   L5 = 3.9001345298901240f;
    const float L6 = 4.1417094500762920f,   L7 = 4.3485155455967720f;

    auto dlut = [&](unsigned c) -> float {
        float a01 = (c & 1u) ? L1 : L0;
        float a23 = (c & 1u) ? L3 : L2;
        float a45 = (c & 1u) ? L5 : L4;
        float a67 = (c & 1u) ? L7 : L6;
        float b0 = (c & 2u) ? a23 : a01;
        float b1 = (c & 2u) ? a67 : a45;
        float v = (c & 4u) ? b1 : b0;
        if (c >= 8u) v = lut[c];   // rare path: few active lanes
        return v;
    };

    auto pstep = [&](unsigned aw, unsigned xw) {  // 2 packed samples
        unsigned pk = (aw + xw) & 0x7FFF7FFFu;    // no cross-half carry (max 65527)
        unsigned c0 = pk & 0xFFFFu, c1 = pk >> 16;
        unsigned sh0 = (c0 & 3u) << 3, sh1 = (c1 & 3u) << 3;
        unsigned o0 = atomicAdd(&hj[c0 >> 2], 1u << sh0);
        unsigned o1 = atomicAdd(&hj[c1 >> 2], 1u << sh1);
        jacc += dlut((o0 >> sh0) & 255u);
        jacc += dlut((o1 >> sh1) & 255u);
    };

    {   // samples [0, 4096)
        const int i = tid * 8;
        uint4 aw = *(const uint4*)(At + i);
        uint4 xw = *(const uint4*)(Xs + i);
        pstep(aw.x, xw.x); pstep(aw.y, xw.y); pstep(aw.z, xw.z); pstep(aw.w, xw.w);
    }
    if (tid < 511) {   // samples [4096, 8184)
        const int i = 4096 + tid * 8;
        uint4 aw = *(const uint4*)(At + i);
        uint4 xw = *(const uint4*)(Xs + i);
        pstep(aw.x, xw.x); pstep(aw.y, xw.y); pstep(aw.z, xw.z); pstep(aw.w, xw.w);
    }
    if (tid < 5) {     // samples 8184..8188
        unsigned c = ((unsigned)At[8184 + tid] + (unsigned)Xs[8184 + tid]) & 0x7FFFu;
        unsigned sh = (c & 3u) << 3;
        unsigned o = atomicAdd(&hj[c >> 2], 1u << sh);
        jacc += dlut((o >> sh) & 255u);
    }
    __syncthreads();

    // tot term: sum_states tot*log2(tot), tot = SWAR byte-sum of 8 cells (uint2)
    float tpart = 0.0f;
    for (int s = tid; s < 4096; s += 512) {
        uint2 wv = *(const uint2*)&hj[s * 2];
        unsigned s0 = (wv.x & 0x00FF00FFu) + ((wv.x >> 8) & 0x00FF00FFu);
        unsigned s1 = (wv.y & 0x00FF00FFu) + ((wv.y >> 8) & 0x00FF00FFu);
        unsigned ss = s0 + s1;
        unsigned tot = (ss & 0xFFFFu) + (ss >> 16);
        float ft = (float)tot;
        tpart += ft * __log2f(fmaxf(ft, 1.0f));
    }
    float acc = tpart - jacc;   // = N * H(Yf|Yp,Xp)

    #pragma unroll
    for (int off = 32; off > 0; off >>= 1) acc += __shfl_down(acc, off, 64);
    if ((tid & 63) == 0) red[tid >> 6] = acc;
    __syncthreads();
    if (tid == 0) {
        float h2 = (red[0] + red[1] + red[2] + red[3] + red[4] + red[5] + red[6] + red[7])
                   * (1.0f / (float)NSAMP);
        out[blockIdx.x] = fmaxf(0.0f, h_y[tgt] - h2);
    }
}

extern "C" void kernel_launch(void* const* d_in, const int* in_sizes, int n_in,
                              void* d_out, int out_size, void* d_ws, size_t ws_size,
                              hipStream_t stream)
{
    const float* ts = (const float*)d_in[0];
    float* out = (float*)d_out;
    unsigned short* A = (unsigned short*)d_ws;           // 1 MiB
    unsigned short* X = A + P * T;                       // 1 MiB
    float* h_y = (float*)(X + P * T);                    // 256 B
    float* tsT = h_y + 64;                               // 2 MiB
    float* pmin = tsT + P * T;                           // 32 KiB
    float* pmax = pmin + P * NBLK;                       // 32 KiB

    transpose_kernel<<<dim3(NBLK), dim3(256), 0, stream>>>(ts, tsT, pmin, pmax);
    prep_kernel<<<dim3(P), dim3(1024), 0, stream>>>(tsT, pmin, pmax, A, X, h_y);
    pair_kernel<<<dim3(P * P), dim3(512), 0, stream>>>(A, X, h_y, out);
}

// Round 9
// 85.430 us; speedup vs baseline: 1.0526x; 1.0526x over previous
//
#include <hip/hip_runtime.h>

static constexpr int T = 8192;
static constexpr int P = 64;
static constexpr int NSAMP = 8189; // T - HIST - 1
static constexpr int NBLK = 128;   // transpose blocks, 64 rows each

// ---------------- K0: transpose ts[T][64] -> tsT[64][T] + per-series minmax partials
__global__ __launch_bounds__(256) void transpose_kernel(const float* __restrict__ ts,
        float* __restrict__ tsT, float* __restrict__ pmin, float* __restrict__ pmax)
{
    __shared__ float tile[64 * 65];   // stride 65: conflict-benign
    const int tid = threadIdx.x;
    const int r0 = blockIdx.x * 64;
    const float4* ts4 = (const float4*)(ts + r0 * P);
    #pragma unroll
    for (int k = 0; k < 4; ++k) {
        int g = tid + k * 256;          // 0..1023
        int r = g >> 4, c = (g & 15) * 4;
        float4 v = ts4[g];              // coalesced
        float* dst = &tile[r * 65 + c];
        dst[0] = v.x; dst[1] = v.y; dst[2] = v.z; dst[3] = v.w;
    }
    __syncthreads();
    #pragma unroll
    for (int k = 0; k < 4; ++k) {
        int g = tid + k * 256;
        int s = g >> 4, j4 = g & 15;    // series, 4-row chunk
        float a = tile[(j4 * 4 + 0) * 65 + s];
        float b = tile[(j4 * 4 + 1) * 65 + s];
        float c = tile[(j4 * 4 + 2) * 65 + s];
        float d = tile[(j4 * 4 + 3) * 65 + s];
        float4 o; o.x = a; o.y = b; o.z = c; o.w = d;
        *(float4*)(tsT + s * T + r0 + j4 * 4) = o;   // coalesced
        float mn = fminf(fminf(a, b), fminf(c, d));
        float mx = fmaxf(fmaxf(a, b), fmaxf(c, d));
        #pragma unroll
        for (int off = 8; off > 0; off >>= 1) {      // 16 lanes share series s
            mn = fminf(mn, __shfl_down(mn, off, 16));
            mx = fmaxf(mx, __shfl_down(mx, off, 16));
        }
        if (j4 == 0) { pmin[s * NBLK + blockIdx.x] = mn; pmax[s * NBLK + blockIdx.x] = mx; }
    }
}

// ---------------- K1: prep — coalesced column read, bin in regs, emit codes + h_y ---
// Pre-scrambled codes: A[i]=((yp*320)&4095)*8+yf, X[i]=((xp*709)&4095)*8
// (320 = 64*709 mod 4096), so pair-side cell = (A+X)&0x7FFF.
__global__ __launch_bounds__(1024) void prep_kernel(const float* __restrict__ tsT,
        const float* __restrict__ pmin, const float* __restrict__ pmax,
        unsigned short* __restrict__ A, unsigned short* __restrict__ X,
        float* __restrict__ h_y)
{
    __shared__ unsigned char bins[T];   // 8 KiB
    __shared__ unsigned int cy[512];    // 2 KiB
    __shared__ float wred[4];
    const int p = blockIdx.x, tid = threadIdx.x;
    const int lane = tid & 63, wave = tid >> 6;

    if (tid < 128) {   // reduce 128 partials (waves 0,1 fully active)
        float mn = pmin[p * NBLK + tid];
        float mx = pmax[p * NBLK + tid];
        #pragma unroll
        for (int off = 32; off > 0; off >>= 1) {
            mn = fminf(mn, __shfl_down(mn, off, 64));
            mx = fmaxf(mx, __shfl_down(mx, off, 64));
        }
        if (lane == 0) { wred[wave] = mn; wred[2 + wave] = mx; }
    }
    for (int i = tid; i < 512; i += 1024) cy[i] = 0u;
    __syncthreads();
    const float xmin = fminf(wred[0], wred[1]);
    const float xmax = fmaxf(wred[2], wred[3]);
    const float rng = xmax - xmin;
    const float den = rng + 1e-8f;      // reference float32 op order
    const int flat = rng < 1e-8f;

    // bin 8 consecutive values from registers (coalesced float4 loads)
    const float4* c4p = (const float4*)(tsT + p * T);
    float4 v0 = c4p[tid * 2], v1 = c4p[tid * 2 + 1];
    float vv[8] = { v0.x, v0.y, v0.z, v0.w, v1.x, v1.y, v1.z, v1.w };
    unsigned pk0 = 0u, pk1 = 0u;
    #pragma unroll
    for (int j = 0; j < 4; ++j) {
        float n0 = (vv[j] - xmin) / den;       // IEEE div, matches reference
        float n1 = (vv[4 + j] - xmin) / den;
        int b0 = (int)(n0 * 7.0f); b0 = b0 < 0 ? 0 : (b0 > 7 ? 7 : b0);
        int b1 = (int)(n1 * 7.0f); b1 = b1 < 0 ? 0 : (b1 > 7 ? 7 : b1);
        if (flat) { b0 = 0; b1 = 0; }
        pk0 |= (unsigned)b0 << (8 * j);
        pk1 |= (unsigned)b1 << (8 * j);
    }
    *(uint2*)&bins[tid * 8] = make_uint2(pk0, pk1);
    __syncthreads();

    unsigned short* Ap = A + p * T;
    unsigned short* Xp = X + p * T;
    for (int i = tid * 4; i + 3 < NSAMP; i += 4096) {
        unsigned w0 = *(const unsigned*)&bins[i];
        unsigned w1 = *(const unsigned*)&bins[i + 4];
        unsigned long long bb = (unsigned long long)w0 | ((unsigned long long)w1 << 32);
        ushort4 av, xv;
        unsigned short* ap = (unsigned short*)&av;
        unsigned short* xp = (unsigned short*)&xv;
        #pragma unroll
        for (int j = 0; j < 4; ++j) {
            unsigned b1 = (unsigned)(bb >> (8 * (j + 1))) & 255u;
            unsigned b2 = (unsigned)(bb >> (8 * (j + 2))) & 255u;
            unsigned b3 = (unsigned)(bb >> (8 * (j + 3))) & 255u;
            unsigned yp = b2 + 8u * b1;
            ap[j] = (unsigned short)(((yp * 320u) & 4095u) * 8u + b3);
            xp[j] = (unsigned short)(((yp * 709u) & 4095u) * 8u);
            atomicAdd(&cy[yp * 8u + b3], 1u);
        }
        *(ushort4*)(Ap + i) = av;
        *(ushort4*)(Xp + i) = xv;
    }
    if (tid == 0) {  // tail: sample 8188
        unsigned b1 = bins[NSAMP], b2 = bins[NSAMP + 1], b3 = bins[NSAMP + 2];
        unsigned yp = b2 + 8u * b1;
        Ap[NSAMP - 1] = (unsigned short)(((yp * 320u) & 4095u) * 8u + b3);
        Xp[NSAMP - 1] = (unsigned short)(((yp * 709u) & 4095u) * 8u);
        atomicAdd(&cy[yp * 8u + b3], 1u);
    }
    __syncthreads();

    if (tid < 64) {
        float tot = 0.0f, sc = 0.0f;
        #pragma unroll
        for (int v = 0; v < 8; ++v) {
            unsigned c = cy[tid * 8 + v];
            if (c) { float fc = (float)c; tot += fc; sc += fc * log2f(fc); }
        }
        float acc = (tot >= 2.0f) ? (tot * log2f(tot) - sc) : 0.0f;
        #pragma unroll
        for (int off = 32; off > 0; off >>= 1) acc += __shfl_down(acc, off, 64);
        if (tid == 0) h_y[p] = acc * (1.0f / (float)NSAMP);
    }
}

// ---------------- K2: pair TE — quad-batched atomic-rtn + delta-LUT ----------------
// Joint hist 32768 u8 cells (32 KiB). sum_cells c*log2 c via telescoping:
// jacc += lut[old] per sample, lut[c]=(c+1)log2(c+1)-c*log2 c.
// Batch of 4: issue 4 independent atomic-rtn, THEN the 4 dependent LUT reads —
// one lgkmcnt drain amortized over 4 samples. Named scalars only (no arrays):
// must stay <=64 VGPR under __launch_bounds__(512,8) or it spills (R7 lesson).
// Tot term: slim SWAR sweep + 1 log/state. tot<2 / c<2 masks automatic.
__global__ __launch_bounds__(512, 8) void pair_kernel(const unsigned short* __restrict__ A,
        const unsigned short* __restrict__ X, const float* __restrict__ h_y,
        float* __restrict__ out)
{
    const int src = blockIdx.x >> 6, tgt = blockIdx.x & 63, tid = threadIdx.x;
    if (src == tgt) { if (tid == 0) out[blockIdx.x] = 0.0f; return; }

    __shared__ unsigned int hj[8192];   // 32768 u8 cells
    __shared__ float lut[256];          // delta LUT
    __shared__ float red[8];

    if (tid < 256) {
        float fc = (float)tid;
        float f0 = (tid == 0) ? 0.0f : fc * log2f(fc);
        lut[tid] = (fc + 1.0f) * log2f(fc + 1.0f) - f0;
    }
    uint4* z = (uint4*)hj;
    for (int i = tid; i < 2048; i += 512) z[i] = make_uint4(0u, 0u, 0u, 0u);
    __syncthreads();

    const unsigned short* At = A + tgt * T;
    const unsigned short* Xs = X + src * T;
    float jacc = 0.0f;

    // 4 samples per batch: all 4 atomics issued before the 4 dependent reads
    auto quad = [&](unsigned awA, unsigned xwA, unsigned awB, unsigned xwB) {
        unsigned pkA = (awA + xwA) & 0x7FFF7FFFu;   // packed 2-sample add,
        unsigned pkB = (awB + xwB) & 0x7FFF7FFFu;   // no cross-half carry
        unsigned c0 = pkA & 0xFFFFu, c1 = pkA >> 16;
        unsigned c2 = pkB & 0xFFFFu, c3 = pkB >> 16;
        unsigned sh0 = (c0 & 3u) << 3, sh1 = (c1 & 3u) << 3;
        unsigned sh2 = (c2 & 3u) << 3, sh3 = (c3 & 3u) << 3;
        unsigned o0 = atomicAdd(&hj[c0 >> 2], 1u << sh0);
        unsigned o1 = atomicAdd(&hj[c1 >> 2], 1u << sh1);
        unsigned o2 = atomicAdd(&hj[c2 >> 2], 1u << sh2);
        unsigned o3 = atomicAdd(&hj[c3 >> 2], 1u << sh3);
        float s = lut[(o0 >> sh0) & 255u] + lut[(o1 >> sh1) & 255u]
                + lut[(o2 >> sh2) & 255u] + lut[(o3 >> sh3) & 255u];
        jacc += s;
    };

    {   // samples [0, 4096)
        const int i = tid * 8;
        uint4 aw = *(const uint4*)(At + i);
        uint4 xw = *(const uint4*)(Xs + i);
        quad(aw.x, xw.x, aw.y, xw.y);
        quad(aw.z, xw.z, aw.w, xw.w);
    }
    if (tid < 511) {   // samples [4096, 8184)
        const int i = 4096 + tid * 8;
        uint4 aw = *(const uint4*)(At + i);
        uint4 xw = *(const uint4*)(Xs + i);
        quad(aw.x, xw.x, aw.y, xw.y);
        quad(aw.z, xw.z, aw.w, xw.w);
    }
    if (tid < 5) {     // samples 8184..8188
        unsigned c = ((unsigned)At[8184 + tid] + (unsigned)Xs[8184 + tid]) & 0x7FFFu;
        unsigned sh = (c & 3u) << 3;
        unsigned o = atomicAdd(&hj[c >> 2], 1u << sh);
        jacc += lut[(o >> sh) & 255u];
    }
    __syncthreads();

    // tot term: sum_states tot*log2(tot), tot = SWAR byte-sum of 8 cells (uint2)
    float tpart = 0.0f;
    for (int s = tid; s < 4096; s += 512) {
        uint2 wv = *(const uint2*)&hj[s * 2];
        unsigned s0 = (wv.x & 0x00FF00FFu) + ((wv.x >> 8) & 0x00FF00FFu);
        unsigned s1 = (wv.y & 0x00FF00FFu) + ((wv.y >> 8) & 0x00FF00FFu);
        unsigned ss = s0 + s1;
        unsigned tot = (ss & 0xFFFFu) + (ss >> 16);
        float ft = (float)tot;
        tpart += ft * __log2f(fmaxf(ft, 1.0f));
    }
    float acc = tpart - jacc;   // = N * H(Yf|Yp,Xp)

    #pragma unroll
    for (int off = 32; off > 0; off >>= 1) acc += __shfl_down(acc, off, 64);
    if ((tid & 63) == 0) red[tid >> 6] = acc;
    __syncthreads();
    if (tid == 0) {
        float h2 = (red[0] + red[1] + red[2] + red[3] + red[4] + red[5] + red[6] + red[7])
                   * (1.0f / (float)NSAMP);
        out[blockIdx.x] = fmaxf(0.0f, h_y[tgt] - h2);
    }
}

extern "C" void kernel_launch(void* const* d_in, const int* in_sizes, int n_in,
                              void* d_out, int out_size, void* d_ws, size_t ws_size,
                              hipStream_t stream)
{
    const float* ts = (const float*)d_in[0];
    float* out = (float*)d_out;
    unsigned short* A = (unsigned short*)d_ws;           // 1 MiB
    unsigned short* X = A + P * T;                       // 1 MiB
    float* h_y = (float*)(X + P * T);                    // 256 B
    float* tsT = h_y + 64;                               // 2 MiB
    float* pmin = tsT + P * T;                           // 32 KiB
    float* pmax = pmin + P * NBLK;                       // 32 KiB

    transpose_kernel<<<dim3(NBLK), dim3(256), 0, stream>>>(ts, tsT, pmin, pmax);
    prep_kernel<<<dim3(P), dim3(1024), 0, stream>>>(tsT, pmin, pmax, A, X, h_y);
    pair_kernel<<<dim3(P * P), dim3(512), 0, stream>>>(A, X, h_y, out);
}